// Round 2
// baseline (14319.099 us; speedup 1.0000x reference)
//
#include <hip/hip_runtime.h>
#include <hip/hip_cooperative_groups.h>
#include <math.h>

namespace cg = cooperative_groups;

#define EPS   1e-6f
#define NDIM  8192
#define NSTEPS 50
// exp(-C/gamma) = exp2(C * SCALE), SCALE = -log2(e)/0.1
#define SCALE (-14.426950408889634f)
// b-vector granule: 8 floats padded to 12 (48 B). Lane stride 48 B tiles all
// 32 banks exactly twice per 16-lane ds_read_b128 phase -> conflict-free.
#define GPAD 12

typedef float v4f __attribute__((ext_vector_type(4)));

__device__ __forceinline__ float bf16lo(unsigned u) { return __uint_as_float(u << 16); }
__device__ __forceinline__ float bf16hi(unsigned u) { return __uint_as_float(u & 0xffff0000u); }

__device__ __forceinline__ unsigned pack2bf16(float a, float b) {
  unsigned ua = __float_as_uint(a), ub = __float_as_uint(b);
  ua = (ua + 0x7fffu + ((ua >> 16) & 1u)) >> 16;
  ub = (ub + 0x7fffu + ((ub >> 16) & 1u)) & 0xffff0000u;
  return ua | ub;
}

// agent-scope (device-coherent) scalar load/store: required for cross-XCD
// visibility inside the fused cooperative kernel (per-XCD L2 not coherent).
__device__ __forceinline__ float aload(const float* p) {
  return __hip_atomic_load(p, __ATOMIC_RELAXED, __HIP_MEMORY_SCOPE_AGENT);
}
__device__ __forceinline__ void astore(float* p, float v) {
  __hip_atomic_store(p, v, __ATOMIC_RELAXED, __HIP_MEMORY_SCOPE_AGENT);
}

// ---- Prologue: K = bf16(exp(-C/gamma)), 8 elems/thread -------------------
__global__ __launch_bounds__(1024) void prologue_k(const float4* __restrict__ C,
                                                   uint4* __restrict__ K) {
  int tid = blockIdx.x * 1024 + threadIdx.x;   // 8192 blocks
  float4 c0 = C[tid * 2], c1 = C[tid * 2 + 1];
  uint4 o;
  o.x = pack2bf16(exp2f(c0.x * SCALE), exp2f(c0.y * SCALE));
  o.y = pack2bf16(exp2f(c0.z * SCALE), exp2f(c0.w * SCALE));
  o.z = pack2bf16(exp2f(c1.x * SCALE), exp2f(c1.y * SCALE));
  o.w = pack2bf16(exp2f(c1.z * SCALE), exp2f(c1.w * SCALE));
  K[tid] = o;
}

// ---- Fused 50-iteration Sinkhorn loop (cooperative, 256 blocks x 1024) ----
// Per iteration:
//   phase A: b_j=(s_j+eps)/z_j into LDS (padded), zero zcur slice,
//            2-row-per-wave GEMV y=Kb, a=(d+eps)/y   -> threadfence, grid.sync
//   phase B: col GEMV z=K^T a, LDS partial reduce, atomicAdd into zcur
//            -> threadfence, grid.sync
__global__ __launch_bounds__(1024) void fused_k(const uint4* __restrict__ K,
                                                const float* __restrict__ d,
                                                const float* __restrict__ s,
                                                float* z0, float* z1,
                                                float* a) {
  cg::grid_group grid = cg::this_grid();
  __shared__ float smem[1024 * GPAD];   // 48 KB: b-granules in A, part[8192] in B
  __shared__ float as_[256];
  const int t = threadIdx.x, bid = blockIdx.x;
  const int wave = t >> 6, lane = t & 63;

  for (int it = 0; it < NSTEPS; ++it) {
    float* zc = (it & 1) ? z1 : z0;
    float* zp = (it & 1) ? z0 : z1;

    // ---- phase A: fill b into padded LDS (1 granule of 8 per thread) ----
    {
      float bv[8];
      if (it == 0) {
        const float E = 2.718281828459045f;
        #pragma unroll
        for (int k = 0; k < 8; k++) bv[k] = E;
      } else {
        const float4* s4 = (const float4*)s;
        float4 sa = s4[2 * t], sb = s4[2 * t + 1];
        float sv[8] = {sa.x, sa.y, sa.z, sa.w, sb.x, sb.y, sb.z, sb.w};
        #pragma unroll
        for (int k = 0; k < 8; k++)
          bv[k] = (sv[k] + EPS) / aload(&zp[8 * t + k]);
      }
      float4 lo = {bv[0], bv[1], bv[2], bv[3]};
      float4 hi = {bv[4], bv[5], bv[6], bv[7]};
      *(float4*)&smem[t * GPAD]     = lo;
      *(float4*)&smem[t * GPAD + 4] = hi;
    }
    if (t < 32) astore(&zc[bid * 32 + t], 0.f);   // zero before B's atomics
    __syncthreads();

    // ---- phase A: row GEMV, 2 rows per wave sharing each b-read ----
    {
      int row0 = bid * 32 + wave, row1 = row0 + 16;
      const uint4* K0 = K + (size_t)row0 * 1024;
      const uint4* K1 = K + (size_t)row1 * 1024;
      float acc0 = 0.f, acc1 = 0.f;
      #pragma unroll 4
      for (int k = 0; k < 16; k++) {
        int idx = k * 64 + lane;
        uint4 q0 = K0[idx], q1 = K1[idx];
        const float* bp = &smem[idx * GPAD];
        float4 b0 = *(const float4*)bp;
        float4 b1 = *(const float4*)(bp + 4);
        acc0 += bf16lo(q0.x) * b0.x + bf16hi(q0.x) * b0.y
              + bf16lo(q0.y) * b0.z + bf16hi(q0.y) * b0.w
              + bf16lo(q0.z) * b1.x + bf16hi(q0.z) * b1.y
              + bf16lo(q0.w) * b1.z + bf16hi(q0.w) * b1.w;
        acc1 += bf16lo(q1.x) * b0.x + bf16hi(q1.x) * b0.y
              + bf16lo(q1.y) * b0.z + bf16hi(q1.y) * b0.w
              + bf16lo(q1.z) * b1.x + bf16hi(q1.z) * b1.y
              + bf16lo(q1.w) * b1.z + bf16hi(q1.w) * b1.w;
      }
      #pragma unroll
      for (int off = 32; off; off >>= 1) {
        acc0 += __shfl_down(acc0, off, 64);
        acc1 += __shfl_down(acc1, off, 64);
      }
      if (lane == 0) {
        astore(&a[row0], (d[row0] + EPS) / acc0);
        astore(&a[row1], (d[row1] + EPS) / acc1);
      }
    }
    __threadfence();
    grid.sync();

    // ---- phase B: col GEMV z = K^T a ----
    {
      int cgc = bid & 7, rg = bid >> 3;
      if (t < 256) as_[t] = aload(&a[rg * 256 + t]);
      __syncthreads();
      int ct = t & 127, rl = t >> 7;
      float acc[8];
      #pragma unroll
      for (int k = 0; k < 8; k++) acc[k] = 0.f;
      int base = cgc * 128 + ct;
      for (int rr = 0; rr < 32; rr++) {
        int r = rg * 256 + rl * 32 + rr;
        uint4 q = K[(size_t)r * 1024 + base];
        float av = as_[rl * 32 + rr];
        acc[0] += bf16lo(q.x) * av; acc[1] += bf16hi(q.x) * av;
        acc[2] += bf16lo(q.y) * av; acc[3] += bf16hi(q.y) * av;
        acc[4] += bf16lo(q.z) * av; acc[5] += bf16hi(q.z) * av;
        acc[6] += bf16lo(q.w) * av; acc[7] += bf16hi(q.w) * av;
      }
      float* pp = &smem[rl * 1024 + ct * 8];
      #pragma unroll
      for (int k = 0; k < 8; k++) pp[k] = acc[k];
      __syncthreads();
      float sum = 0.f;
      #pragma unroll
      for (int r2 = 0; r2 < 8; r2++) sum += smem[r2 * 1024 + t];
      atomicAdd(&zc[cgc * 1024 + t], sum);   // device-scope, 32 adds/address
    }
    __threadfence();
    grid.sync();
  }
}

// ---- Epilogue: P = a_i * exp(-C/gamma) * b_j (fp32 C, nontemporal I/O) ----
__global__ __launch_bounds__(1024) void epilogue_k(const float4* __restrict__ C,
                                                   const float* __restrict__ a,
                                                   const float* __restrict__ zlast,
                                                   const float* __restrict__ s,
                                                   float4* __restrict__ out) {
  __shared__ float4 bs4[2048];
  int t = threadIdx.x;
  {
    const float4* s4 = (const float4*)s;
    const float4* z4 = (const float4*)zlast;
    float4 sa = s4[2 * t], sb = s4[2 * t + 1];
    float4 za = z4[2 * t], zb = z4[2 * t + 1];
    float4 ba = {(sa.x + EPS) / za.x, (sa.y + EPS) / za.y,
                 (sa.z + EPS) / za.z, (sa.w + EPS) / za.w};
    float4 bb = {(sb.x + EPS) / zb.x, (sb.y + EPS) / zb.y,
                 (sb.z + EPS) / zb.z, (sb.w + EPS) / zb.w};
    bs4[2 * t] = ba; bs4[2 * t + 1] = bb;
  }
  __syncthreads();
  int wave = t >> 6, lane = t & 63;
  for (int rr = wave; rr < 32; rr += 16) {
    int row = blockIdx.x * 32 + rr;
    float av = a[row];
    const v4f* Crow = (const v4f*)(C + (size_t)row * 2048);
    v4f* Orow = (v4f*)(out + (size_t)row * 2048);
    for (int k = 0; k < 32; k++) {
      int idx = k * 64 + lane;
      v4f c = __builtin_nontemporal_load(&Crow[idx]);
      float4 bq = bs4[idx];
      v4f p;
      p.x = av * bq.x * exp2f(c.x * SCALE);
      p.y = av * bq.y * exp2f(c.y * SCALE);
      p.z = av * bq.z * exp2f(c.z * SCALE);
      p.w = av * bq.w * exp2f(c.w * SCALE);
      __builtin_nontemporal_store(p, &Orow[idx]);
    }
  }
}

// ---- Fallback (workspace too small for K): per-iteration kernels on C ----
__global__ __launch_bounds__(1024) void phaseA_c(const float4* __restrict__ C,
                                                 const float* __restrict__ zprev,
                                                 const float* __restrict__ s,
                                                 const float* __restrict__ d,
                                                 float* __restrict__ a,
                                                 float* __restrict__ zcur) {
  __shared__ float bs[NDIM];
  int t = threadIdx.x;
  float4* bs4 = (float4*)bs;
  if (zprev) {
    const float4* zp4 = (const float4*)zprev;
    const float4* s4 = (const float4*)s;
    float4 za = zp4[2 * t], zb = zp4[2 * t + 1];
    float4 sa = s4[2 * t], sb = s4[2 * t + 1];
    float4 ba = {(sa.x + EPS) / za.x, (sa.y + EPS) / za.y,
                 (sa.z + EPS) / za.z, (sa.w + EPS) / za.w};
    float4 bb = {(sb.x + EPS) / zb.x, (sb.y + EPS) / zb.y,
                 (sb.z + EPS) / zb.z, (sb.w + EPS) / zb.w};
    bs4[2 * t] = ba; bs4[2 * t + 1] = bb;
  } else {
    const float E = 2.718281828459045f;
    float4 e4 = {E, E, E, E};
    bs4[2 * t] = e4; bs4[2 * t + 1] = e4;
  }
  if (t < 32) zcur[blockIdx.x * 32 + t] = 0.f;
  __syncthreads();
  int wave = t >> 6, lane = t & 63;
  for (int rr = wave; rr < 32; rr += 16) {
    int row = blockIdx.x * 32 + rr;
    const float4* Cq = C + (size_t)row * 2048;
    float acc = 0.f;
    for (int k = 0; k < 16; k++) {
      int idx = k * 64 + lane;
      float4 c0 = Cq[idx * 2], c1 = Cq[idx * 2 + 1];
      const float4* bp = (const float4*)&bs[idx * 8];
      float4 b0 = bp[0], b1 = bp[1];
      acc += exp2f(c0.x * SCALE) * b0.x + exp2f(c0.y * SCALE) * b0.y
           + exp2f(c0.z * SCALE) * b0.z + exp2f(c0.w * SCALE) * b0.w
           + exp2f(c1.x * SCALE) * b1.x + exp2f(c1.y * SCALE) * b1.y
           + exp2f(c1.z * SCALE) * b1.z + exp2f(c1.w * SCALE) * b1.w;
    }
    #pragma unroll
    for (int off = 32; off; off >>= 1) acc += __shfl_down(acc, off, 64);
    if (lane == 0) a[row] = (d[row] + EPS) / acc;
  }
}

__global__ __launch_bounds__(1024) void phaseB_c(const float4* __restrict__ C,
                                                 const float* __restrict__ a,
                                                 float* __restrict__ zcur) {
  __shared__ float as_[256];
  __shared__ float part[8192];
  int t = threadIdx.x;
  int cgc = blockIdx.x & 7, rg = blockIdx.x >> 3;
  if (t < 256) as_[t] = a[rg * 256 + t];
  __syncthreads();
  int ct = t & 127, rl = t >> 7;
  float acc[8];
  #pragma unroll
  for (int k = 0; k < 8; k++) acc[k] = 0.f;
  int base = cgc * 256 + ct * 2;
  for (int rr = 0; rr < 32; rr++) {
    int r = rg * 256 + rl * 32 + rr;
    float4 c0 = C[(size_t)r * 2048 + base], c1 = C[(size_t)r * 2048 + base + 1];
    float av = as_[rl * 32 + rr];
    acc[0] += exp2f(c0.x * SCALE) * av; acc[1] += exp2f(c0.y * SCALE) * av;
    acc[2] += exp2f(c0.z * SCALE) * av; acc[3] += exp2f(c0.w * SCALE) * av;
    acc[4] += exp2f(c1.x * SCALE) * av; acc[5] += exp2f(c1.y * SCALE) * av;
    acc[6] += exp2f(c1.z * SCALE) * av; acc[7] += exp2f(c1.w * SCALE) * av;
  }
  float* pp = &part[rl * 1024 + ct * 8];
  #pragma unroll
  for (int k = 0; k < 8; k++) pp[k] = acc[k];
  __syncthreads();
  float sum = 0.f;
  #pragma unroll
  for (int r2 = 0; r2 < 8; r2++) sum += part[r2 * 1024 + t];
  atomicAdd(&zcur[cgc * 1024 + t], sum);
}

extern "C" void kernel_launch(void* const* d_in, const int* in_sizes, int n_in,
                              void* d_out, int out_size, void* d_ws, size_t ws_size,
                              hipStream_t stream) {
  const float* C = (const float*)d_in[0];
  const float* dd = (const float*)d_in[1];
  const float* ss = (const float*)d_in[2];

  float* z0 = (float*)d_ws;
  float* z1 = z0 + NDIM;
  float* a  = z1 + NDIM;
  char* kbase = (char*)d_ws + 131072;
  size_t kneed = 131072 + (size_t)NDIM * NDIM * 2;  // vectors + bf16 K
  bool usek = ws_size >= kneed;

  if (usek) {
    prologue_k<<<8192, 1024, 0, stream>>>((const float4*)C, (uint4*)kbase);
    const uint4* Kp = (const uint4*)kbase;
    void* kargs[] = {(void*)&Kp, (void*)&dd, (void*)&ss,
                     (void*)&z0, (void*)&z1, (void*)&a};
    hipLaunchCooperativeKernel((void*)fused_k, dim3(256), dim3(1024),
                               kargs, 0, stream);
  } else {
    for (int it = 0; it < NSTEPS; ++it) {
      float* zc = (it & 1) ? z1 : z0;
      const float* zp = (it == 0) ? nullptr : ((it & 1) ? z0 : z1);
      phaseA_c<<<256, 1024, 0, stream>>>((const float4*)C, zp, ss, dd, a, zc);
      phaseB_c<<<256, 1024, 0, stream>>>((const float4*)C, a, zc);
    }
  }
  const float* zlast = ((NSTEPS - 1) & 1) ? z1 : z0;
  epilogue_k<<<256, 1024, 0, stream>>>((const float4*)C, a, zlast, ss, (float4*)d_out);
}

// Round 3
// 1889.561 us; speedup vs baseline: 7.5780x; 7.5780x over previous
//
#include <hip/hip_runtime.h>
#include <math.h>

#define EPS   1e-6f
#define NDIM  8192
#define NSTEPS 50
// exp(-C/gamma) = exp2(C * SCALE), SCALE = -log2(e)/0.1
#define SCALE (-14.426950408889634f)
// K~ = 256*exp(-C/gamma): fits OCP e4m3 [2^-9 .. 448]; min value 256*e^-10=0.0116 ok
#define KLOG2 8.0f
#define KSCALE 256.0f
// b-granule pad: 8 floats stored with stride 12 (48B) -> ds_read_b128 2-way (free)
#define GPAD 12

typedef float v2f __attribute__((ext_vector_type(2)));
typedef float v4f __attribute__((ext_vector_type(4)));

__device__ __forceinline__ v2f cvt2lo(unsigned w) {
  return __builtin_amdgcn_cvt_pk_f32_fp8(w, false);   // bytes 0,1
}
__device__ __forceinline__ v2f cvt2hi(unsigned w) {
  return __builtin_amdgcn_cvt_pk_f32_fp8(w, true);    // bytes 2,3
}

// ---- Prologue: K8 = e4m3(256*exp(-C/gamma)), 8 elems/thread --------------
__global__ __launch_bounds__(1024) void prologue_k(const float4* __restrict__ C,
                                                   uint2* __restrict__ K8) {
  int tid = blockIdx.x * 1024 + threadIdx.x;    // 8192 blocks
  v4f c0 = __builtin_nontemporal_load((const v4f*)C + (size_t)tid * 2);
  v4f c1 = __builtin_nontemporal_load((const v4f*)C + (size_t)tid * 2 + 1);
  unsigned lo = 0, hi = 0;
  lo = __builtin_amdgcn_cvt_pk_fp8_f32(exp2f(c0.x * SCALE + KLOG2),
                                       exp2f(c0.y * SCALE + KLOG2), lo, false);
  lo = __builtin_amdgcn_cvt_pk_fp8_f32(exp2f(c0.z * SCALE + KLOG2),
                                       exp2f(c0.w * SCALE + KLOG2), lo, true);
  hi = __builtin_amdgcn_cvt_pk_fp8_f32(exp2f(c1.x * SCALE + KLOG2),
                                       exp2f(c1.y * SCALE + KLOG2), hi, false);
  hi = __builtin_amdgcn_cvt_pk_fp8_f32(exp2f(c1.z * SCALE + KLOG2),
                                       exp2f(c1.w * SCALE + KLOG2), hi, true);
  uint2 o; o.x = lo; o.y = hi;
  K8[tid] = o;
}

// ---- Phase A: y = K~ b (row GEMV); a=(d+eps)/y; zero zcur ----------------
// 256 blocks x 1024 threads; wave w handles rows w and w+16 sharing b-reads.
template <bool USEK>
__global__ __launch_bounds__(1024) void phaseA_k(const void* __restrict__ Kp,
                                                 const float* __restrict__ zprev,
                                                 const float* __restrict__ s,
                                                 const float* __restrict__ d,
                                                 float* __restrict__ a,
                                                 float* __restrict__ zcur) {
  __shared__ float bs[1024 * GPAD];   // 48 KB padded b-granules
  int t = threadIdx.x;
  {
    float4 ba, bb;
    if (zprev) {
      const float4* zp4 = (const float4*)zprev;
      const float4* s4 = (const float4*)s;
      float4 za = zp4[2 * t], zb = zp4[2 * t + 1];
      float4 sa = s4[2 * t], sb = s4[2 * t + 1];
      ba.x = (sa.x + EPS) / za.x; ba.y = (sa.y + EPS) / za.y;
      ba.z = (sa.z + EPS) / za.z; ba.w = (sa.w + EPS) / za.w;
      bb.x = (sb.x + EPS) / zb.x; bb.y = (sb.y + EPS) / zb.y;
      bb.z = (sb.z + EPS) / zb.z; bb.w = (sb.w + EPS) / zb.w;
    } else {
      const float E = 2.718281828459045f;
      ba = float4{E, E, E, E}; bb = ba;
    }
    *(float4*)&bs[t * GPAD]     = ba;
    *(float4*)&bs[t * GPAD + 4] = bb;
  }
  if (t < 32) zcur[blockIdx.x * 32 + t] = 0.f;
  __syncthreads();

  int wave = t >> 6, lane = t & 63;
  int row0 = blockIdx.x * 32 + wave, row1 = row0 + 16;
  float acc0 = 0.f, acc1 = 0.f;
  if (USEK) {
    const uint2* K0 = (const uint2*)Kp + (size_t)row0 * 1024;
    const uint2* K1 = (const uint2*)Kp + (size_t)row1 * 1024;
    #pragma unroll 4
    for (int k = 0; k < 16; k++) {
      int idx = k * 64 + lane;
      uint2 q0 = K0[idx], q1 = K1[idx];
      const float4* bp = (const float4*)&bs[idx * GPAD];
      float4 b0 = bp[0], b1 = bp[1];
      v2f f;
      f = cvt2lo(q0.x); acc0 += f.x * b0.x + f.y * b0.y;
      f = cvt2hi(q0.x); acc0 += f.x * b0.z + f.y * b0.w;
      f = cvt2lo(q0.y); acc0 += f.x * b1.x + f.y * b1.y;
      f = cvt2hi(q0.y); acc0 += f.x * b1.z + f.y * b1.w;
      f = cvt2lo(q1.x); acc1 += f.x * b0.x + f.y * b0.y;
      f = cvt2hi(q1.x); acc1 += f.x * b0.z + f.y * b0.w;
      f = cvt2lo(q1.y); acc1 += f.x * b1.x + f.y * b1.y;
      f = cvt2hi(q1.y); acc1 += f.x * b1.z + f.y * b1.w;
    }
  } else {
    const float4* C0 = (const float4*)Kp + (size_t)row0 * 2048;
    const float4* C1 = (const float4*)Kp + (size_t)row1 * 2048;
    for (int k = 0; k < 16; k++) {
      int idx = k * 64 + lane;
      const float4* bp = (const float4*)&bs[idx * GPAD];
      float4 b0 = bp[0], b1 = bp[1];
      float4 c0 = C0[idx * 2], c1 = C0[idx * 2 + 1];
      acc0 += exp2f(c0.x * SCALE + KLOG2) * b0.x + exp2f(c0.y * SCALE + KLOG2) * b0.y
            + exp2f(c0.z * SCALE + KLOG2) * b0.z + exp2f(c0.w * SCALE + KLOG2) * b0.w
            + exp2f(c1.x * SCALE + KLOG2) * b1.x + exp2f(c1.y * SCALE + KLOG2) * b1.y
            + exp2f(c1.z * SCALE + KLOG2) * b1.z + exp2f(c1.w * SCALE + KLOG2) * b1.w;
      c0 = C1[idx * 2]; c1 = C1[idx * 2 + 1];
      acc1 += exp2f(c0.x * SCALE + KLOG2) * b0.x + exp2f(c0.y * SCALE + KLOG2) * b0.y
            + exp2f(c0.z * SCALE + KLOG2) * b0.z + exp2f(c0.w * SCALE + KLOG2) * b0.w
            + exp2f(c1.x * SCALE + KLOG2) * b1.x + exp2f(c1.y * SCALE + KLOG2) * b1.y
            + exp2f(c1.z * SCALE + KLOG2) * b1.z + exp2f(c1.w * SCALE + KLOG2) * b1.w;
    }
  }
  #pragma unroll
  for (int off = 32; off; off >>= 1) {
    acc0 += __shfl_down(acc0, off, 64);
    acc1 += __shfl_down(acc1, off, 64);
  }
  if (lane == 0) {
    a[row0] = (d[row0] + EPS) / acc0;
    a[row1] = (d[row1] + EPS) / acc1;
  }
}

// ---- Phase B: z = K~^T a (col GEMV), atomic accumulate into zcur ---------
// 256 blocks = 8 col-groups (1024 cols) x 32 row-groups (256 rows).
// Threads: 128 col-threads (8 cols each) x 8 row-lanes (32 rows each).
// part[] writes XOR-half-swizzled -> 2-way bank access (free).
template <bool USEK>
__global__ __launch_bounds__(1024) void phaseB_k(const void* __restrict__ Kp,
                                                 const float* __restrict__ a,
                                                 float* __restrict__ zcur) {
  __shared__ float as_[256];
  __shared__ float part[8 * 1024];
  int t = threadIdx.x;
  int cg = blockIdx.x & 7, rg = blockIdx.x >> 3;
  if (t < 256) as_[t] = a[rg * 256 + t];
  __syncthreads();
  int ct = t & 127, rl = t >> 7;
  float acc[8];
  #pragma unroll
  for (int k = 0; k < 8; k++) acc[k] = 0.f;
  int r0 = rg * 256 + rl * 32;
  if (USEK) {
    const uint2* K2 = (const uint2*)Kp;
    int base = cg * 128 + ct;                 // uint2 index within row (1024/row)
    #pragma unroll 4
    for (int rr = 0; rr < 32; rr++) {
      uint2 q = K2[(size_t)(r0 + rr) * 1024 + base];
      float av = as_[rl * 32 + rr];
      v2f f;
      f = cvt2lo(q.x); acc[0] += f.x * av; acc[1] += f.y * av;
      f = cvt2hi(q.x); acc[2] += f.x * av; acc[3] += f.y * av;
      f = cvt2lo(q.y); acc[4] += f.x * av; acc[5] += f.y * av;
      f = cvt2hi(q.y); acc[6] += f.x * av; acc[7] += f.y * av;
    }
  } else {
    const float4* Cq = (const float4*)Kp;
    int base = cg * 256 + ct * 2;
    for (int rr = 0; rr < 32; rr++) {
      int r = r0 + rr;
      float4 c0 = Cq[(size_t)r * 2048 + base], c1 = Cq[(size_t)r * 2048 + base + 1];
      float av = as_[rl * 32 + rr];
      acc[0] += exp2f(c0.x * SCALE + KLOG2) * av; acc[1] += exp2f(c0.y * SCALE + KLOG2) * av;
      acc[2] += exp2f(c0.z * SCALE + KLOG2) * av; acc[3] += exp2f(c0.w * SCALE + KLOG2) * av;
      acc[4] += exp2f(c1.x * SCALE + KLOG2) * av; acc[5] += exp2f(c1.y * SCALE + KLOG2) * av;
      acc[6] += exp2f(c1.z * SCALE + KLOG2) * av; acc[7] += exp2f(c1.w * SCALE + KLOG2) * av;
    }
  }
  // swizzled store: swap float4 halves when bit2 of ct set -> 2-way banks
  int sw = ((ct >> 2) & 1) << 2;
  float4 lo4 = {acc[0], acc[1], acc[2], acc[3]};
  float4 hi4 = {acc[4], acc[5], acc[6], acc[7]};
  *(float4*)&part[rl * 1024 + ct * 8 + (0 ^ sw)] = lo4;
  *(float4*)&part[rl * 1024 + ct * 8 + (4 ^ sw)] = hi4;
  __syncthreads();
  int ridx = t ^ (((t >> 5) & 1) << 2);     // inverse of the half-swap
  float sum = 0.f;
  #pragma unroll
  for (int r2 = 0; r2 < 8; r2++) sum += part[r2 * 1024 + ridx];
  atomicAdd(&zcur[cg * 1024 + t], sum);     // 32 adds per address
}

// ---- Epilogue: P = 256 * a_i * exp(-C/gamma) * b_j (fp32 C, NT I/O) ------
// 512 blocks x 1024 threads; 16 rows/block, 1 row per wave.
__global__ __launch_bounds__(1024) void epilogue_k(const float4* __restrict__ C,
                                                   const float* __restrict__ a,
                                                   const float* __restrict__ zlast,
                                                   const float* __restrict__ s,
                                                   float4* __restrict__ out) {
  __shared__ float4 bs4[2048];
  int t = threadIdx.x;
  {
    const float4* s4 = (const float4*)s;
    const float4* z4 = (const float4*)zlast;
    float4 sa = s4[2 * t], sb = s4[2 * t + 1];
    float4 za = z4[2 * t], zb = z4[2 * t + 1];
    float4 ba = {(sa.x + EPS) / za.x, (sa.y + EPS) / za.y,
                 (sa.z + EPS) / za.z, (sa.w + EPS) / za.w};
    float4 bb = {(sb.x + EPS) / zb.x, (sb.y + EPS) / zb.y,
                 (sb.z + EPS) / zb.z, (sb.w + EPS) / zb.w};
    bs4[2 * t] = ba; bs4[2 * t + 1] = bb;
  }
  __syncthreads();
  int wave = t >> 6, lane = t & 63;
  int row = blockIdx.x * 16 + wave;
  float av = a[row] * KSCALE;
  const v4f* Crow = (const v4f*)(C + (size_t)row * 2048);
  v4f* Orow = (v4f*)(out + (size_t)row * 2048);
  for (int k = 0; k < 32; k++) {
    int idx = k * 64 + lane;
    v4f c = __builtin_nontemporal_load(&Crow[idx]);
    float4 bq = bs4[idx];
    v4f p;
    p.x = av * bq.x * exp2f(c.x * SCALE);
    p.y = av * bq.y * exp2f(c.y * SCALE);
    p.z = av * bq.z * exp2f(c.z * SCALE);
    p.w = av * bq.w * exp2f(c.w * SCALE);
    __builtin_nontemporal_store(p, &Orow[idx]);
  }
}

extern "C" void kernel_launch(void* const* d_in, const int* in_sizes, int n_in,
                              void* d_out, int out_size, void* d_ws, size_t ws_size,
                              hipStream_t stream) {
  const float* C = (const float*)d_in[0];
  const float* dd = (const float*)d_in[1];
  const float* ss = (const float*)d_in[2];

  float* z0 = (float*)d_ws;
  float* z1 = z0 + NDIM;
  float* a  = z1 + NDIM;
  char* kbase = (char*)d_ws + 131072;
  size_t kneed = 131072 + (size_t)NDIM * NDIM;   // vectors + fp8 K
  bool usek = ws_size >= kneed;

  if (usek) {
    prologue_k<<<8192, 1024, 0, stream>>>((const float4*)C, (uint2*)kbase);
  }
  const void* Kp = usek ? (const void*)kbase : (const void*)C;

  for (int it = 0; it < NSTEPS; ++it) {
    float* zc = (it & 1) ? z1 : z0;
    const float* zp = (it == 0) ? nullptr : ((it & 1) ? z0 : z1);
    if (usek) {
      phaseA_k<true><<<256, 1024, 0, stream>>>(Kp, zp, ss, dd, a, zc);
      phaseB_k<true><<<256, 1024, 0, stream>>>(Kp, a, zc);
    } else {
      phaseA_k<false><<<256, 1024, 0, stream>>>(Kp, zp, ss, dd, a, zc);
      phaseB_k<false><<<256, 1024, 0, stream>>>(Kp, a, zc);
    }
  }
  const float* zlast = ((NSTEPS - 1) & 1) ? z1 : z0;
  epilogue_k<<<512, 1024, 0, stream>>>((const float4*)C, a, zlast, ss, (float4*)d_out);
}